// Round 2
// baseline (214.325 us; speedup 1.0000x reference)
//
#include <hip/hip_runtime.h>
#include <math.h>

// B=4, L=1024, D=512, H=8, d=64
#define L_ 1024
#define D_ 512

typedef _Float16 half8 __attribute__((ext_vector_type(8)));
typedef _Float16 half4v __attribute__((ext_vector_type(4)));
typedef _Float16 half2v __attribute__((ext_vector_type(2)));
typedef float floatx4 __attribute__((ext_vector_type(4)));

// ---------- prep: K,Q -> fp16 straight; V -> fp16 transposed Vt[b][h][d][m]
__global__ __launch_bounds__(256) void prep(
    const float* __restrict__ K, const float* __restrict__ Q,
    const float* __restrict__ V,
    _Float16* __restrict__ K16, _Float16* __restrict__ Q16,
    _Float16* __restrict__ Vt)
{
    __shared__ _Float16 tile[64][72];
    const int t = threadIdx.x;
    const int bi = blockIdx.x;
    if (bi < 256) {
        for (int it = 0; it < 16; ++it) {
            size_t f = (size_t)bi * 4096 + it * 256 + t;
            const float4* src; _Float16* dst;
            if (f < 524288) { src = (const float4*)K; dst = K16; }
            else            { src = (const float4*)Q; dst = Q16; f -= 524288; }
            float4 v = src[f];
            half4v h = { (_Float16)v.x, (_Float16)v.y, (_Float16)v.z, (_Float16)v.w };
            *(half4v*)&dst[f * 4] = h;
        }
    } else {
        const int id = bi - 256;            // 512 blocks: 4b x 8h x 16 mtiles
        const int mt = id & 15, h = (id >> 4) & 7, b = id >> 7;
        const float4* Vf4 = (const float4*)V;
        for (int it = 0; it < 4; ++it) {
            const int ml = (t >> 4) + 16 * it;
            const int c4 = t & 15;
            float4 v = Vf4[(size_t)(b * 1024 + mt * 64 + ml) * 128 + h * 16 + c4];
            tile[c4 * 4 + 0][ml] = (_Float16)v.x;
            tile[c4 * 4 + 1][ml] = (_Float16)v.y;
            tile[c4 * 4 + 2][ml] = (_Float16)v.z;
            tile[c4 * 4 + 3][ml] = (_Float16)v.w;
        }
        __syncthreads();
        const int d = t >> 2, seg = t & 3;
        half8 o0 = *(half8*)&tile[d][seg * 16];
        half8 o1 = *(half8*)&tile[d][seg * 16 + 8];
        size_t obase = ((size_t)(b * 8 + h) * 64 + d) * 1024 + mt * 64 + seg * 16;
        *(half8*)&Vt[obase] = o0;
        *(half8*)&Vt[obase + 8] = o1;
    }
}

// ---------- qk_ln: e = exp(LN(K.Q^T) - M) via fp16 MFMA, masked, stored
// coalesced to S[b][h][l][m]. Per-mt contiguous 128x64 chunks are staged in
// a small double-buffered LDS (33 KB -> 4 blocks/CU) and stored immediately,
// overlapping later compute. M = max_h(2.8285*|gamma_h|+|beta_h|) is a
// data-independent LN output bound, so no per-row max pass is needed.
__global__ __launch_bounds__(256) void qk_ln(
    const _Float16* __restrict__ K16, const _Float16* __restrict__ Q16,
    const float* __restrict__ gamma, const float* __restrict__ beta,
    const float* __restrict__ doc,
    _Float16* __restrict__ S, float* __restrict__ spart)
{
    __shared__ _Float16 se[2][128][66];   // 33792 B -> 4 blocks/CU

    const int t  = threadIdx.x;
    const int bi = blockIdx.x;              // 1024 = 4b x 64 lt x 4 q
    const int b  = bi & 3;
    const int lt = (bi >> 2) & 63;
    const int q  = bi >> 8;
    const int wv = t >> 6, lane = t & 63;
    const int col = lane & 15, quad = lane >> 4;
    const int len = (int)doc[b];
    const int lbase = lt * 16;

    float g[8], be[8], M = 0.f;
    #pragma unroll
    for (int h = 0; h < 8; ++h) {
        g[h] = gamma[h]; be[h] = beta[h];
        M = fmaxf(M, 2.8285f * fabsf(g[h]) + fabsf(be[h]));
    }

    const _Float16* Kb = K16 + (size_t)b * 524288;
    const _Float16* Qb = Q16 + (size_t)b * 524288;
    const size_t krow = (size_t)(lbase + col) * 512;

    half8 a0[8], a1[8];
    #pragma unroll
    for (int h = 0; h < 8; ++h) {
        a0[h] = *(const half8*)&Kb[krow + h * 64 + quad * 8];
        a1[h] = *(const half8*)&Kb[krow + h * 64 + 32 + quad * 8];
    }

    float sum[8][4];
    #pragma unroll
    for (int h = 0; h < 8; ++h)
        #pragma unroll
        for (int r = 0; r < 4; ++r) sum[h][r] = 0.f;

    for (int mt = 0; mt < 4; ++mt) {
        // contiguous per-mt chunk: block covers m = q*256 + mt*64 .. +64
        const int m0 = q * 256 + mt * 64 + wv * 16;
        const size_t qrow = (size_t)(m0 + col) * 512;
        floatx4 c[8];
        #pragma unroll
        for (int h = 0; h < 8; ++h) {
            half8 b0 = *(const half8*)&Qb[qrow + h * 64 + quad * 8];
            half8 b1 = *(const half8*)&Qb[qrow + h * 64 + 32 + quad * 8];
            floatx4 z = {0.f, 0.f, 0.f, 0.f};
            z    = __builtin_amdgcn_mfma_f32_16x16x32_f16(a0[h], b0, z, 0, 0, 0);
            c[h] = __builtin_amdgcn_mfma_f32_16x16x32_f16(a1[h], b1, c[h] = z, 0, 0, 0);
        }
        const bool mok = (m0 + col) < len;
        #pragma unroll
        for (int r = 0; r < 4; ++r) {
            const int l = lbase + quad * 4 + r;
            float mu = 0.f;
            #pragma unroll
            for (int h = 0; h < 8; ++h) mu += c[h][r];
            mu *= 0.125f;
            float var = 0.f;
            #pragma unroll
            for (int h = 0; h < 8; ++h) { float dd = c[h][r] - mu; var += dd * dd; }
            var *= 0.125f;
            const float rs = 1.0f / sqrtf(var + 1e-5f);
            const bool keep = mok && (l < len);
            #pragma unroll
            for (int h = 0; h < 8; ++h) {
                float e = 0.f;
                if (keep) {
                    float val = (c[h][r] - mu) * rs * g[h] + be[h];
                    e = __expf(val - M);
                }
                sum[h][r] += e;
                se[mt & 1][h * 16 + quad * 4 + r][wv * 16 + col] = (_Float16)e;
            }
        }
        __syncthreads();
        // store this mt's 128 rows x 64 m chunk (coalesced 128B row segments)
        const int mbase = q * 256 + mt * 64;
        #pragma unroll
        for (int it = 0; it < 4; ++it) {
            const int row = it * 32 + (t >> 3);
            const int h = row >> 4, l = row & 15;
            half8 v = *(half8*)&se[mt & 1][row][(t & 7) * 8];
            *(half8*)&S[((size_t)((b * 8 + h) * 1024 + lbase + l)) * 1024
                        + mbase + (t & 7) * 8] = v;
        }
        // next mt writes the other buffer; the mt+2 reuse is ordered by the
        // intervening __syncthreads (which drains lgkm).
    }

    // reduce row partial sums over the 16 col-lanes of each quad
    #pragma unroll
    for (int h = 0; h < 8; ++h)
        #pragma unroll
        for (int r = 0; r < 4; ++r) {
            float s = sum[h][r];
            s += __shfl_xor(s, 1); s += __shfl_xor(s, 2);
            s += __shfl_xor(s, 4); s += __shfl_xor(s, 8);
            sum[h][r] = s;
        }
    if (col == 0) {
        #pragma unroll
        for (int h = 0; h < 8; ++h)
            #pragma unroll
            for (int r = 0; r < 4; ++r)
                spart[((size_t)((b * 8 + h) * 1024 + lbase + quad * 4 + r)) * 16
                      + q * 4 + wv] = sum[h][r];
    }
}

// ---------- stats_reduce: inv[row] = 1/sum(e) (0 for padded rows)
__global__ __launch_bounds__(256) void stats_reduce(
    const float* __restrict__ spart, const float* __restrict__ doc,
    float* __restrict__ inv)
{
    const int i = blockIdx.x * 256 + threadIdx.x;   // 32768 rows
    const int l = i & 1023;
    const int b = i >> 13;
    const int len = (int)doc[b];
    float s = 0.f;
    #pragma unroll
    for (int j = 0; j < 16; ++j) s += spart[(size_t)i * 16 + j];
    inv[i] = (l < len && s > 0.f) ? 1.0f / s : 0.f;
}

// ---------- pv: pure streaming PV MFMA on raw fp16 e; normalization (inv)
// applied to the fp32 accumulator in the epilogue. No LDS, no shuffles,
// no atomics -> trivially pipelineable. 8-deep register ring prefetch on
// the HBM-streamed e rows; Vt is L2-resident.
__global__ __launch_bounds__(256) void pv(
    const _Float16* __restrict__ S, const _Float16* __restrict__ Vt,
    const float* __restrict__ invp,
    float* __restrict__ out)
{
    const int t = threadIdx.x, wv = t >> 6, lane = t & 63;
    const int col = lane & 15, quad = lane >> 4;
    const int bi = blockIdx.x;            // 512 = 4b x 8h x 16 lb
    const int lb = bi & 15, h = (bi >> 4) & 7, b = bi >> 7;
    const int l0 = lb * 64 + wv * 16;

    const _Float16* Arow = S + ((size_t)(b * 8 + h) * 1024 + l0 + col) * 1024;
    const _Float16* Vb = Vt + (size_t)(b * 8 + h) * 65536;

    floatx4 acc[4] = {{0,0,0,0},{0,0,0,0},{0,0,0,0},{0,0,0,0}};

    half8 ebuf[8];
    #pragma unroll
    for (int i = 0; i < 8; ++i)
        ebuf[i] = *(const half8*)&Arow[i * 32 + quad * 8];

    #pragma unroll
    for (int kc = 0; kc < 32; ++kc) {
        half8 a = ebuf[kc & 7];
        if (kc + 8 < 32)
            ebuf[kc & 7] = *(const half8*)&Arow[(kc + 8) * 32 + quad * 8];
        #pragma unroll
        for (int dt = 0; dt < 4; ++dt) {
            half8 bf = *(const half8*)&Vb[(size_t)(dt * 16 + col) * 1024
                                          + kc * 32 + quad * 8];
            acc[dt] = __builtin_amdgcn_mfma_f32_16x16x32_f16(a, bf, acc[dt], 0, 0, 0);
        }
    }

    #pragma unroll
    for (int r = 0; r < 4; ++r) {
        const int l = l0 + quad * 4 + r;
        const float ivr = invp[(size_t)(b * 8 + h) * 1024 + l];
        float* orow = out + (size_t)(b * 1024 + l) * 512 + h * 64;
        #pragma unroll
        for (int dt = 0; dt < 4; ++dt)
            orow[dt * 16 + col] = acc[dt][r] * ivr;
    }
}

// ---------- wsum: w column sums with m-major ownership.
// wacc[b][m] += sum_l e[l][m] * inv[l]  (summed over h via atomics).
// Coalesced: 256 threads x 8B = full 2KB row per iteration. Per-lane fp32
// register accumulation -> no cross-lane traffic at all.
__global__ __launch_bounds__(256) void wsum(
    const _Float16* __restrict__ S, const float* __restrict__ invp,
    float* __restrict__ wacc)
{
    const int t = threadIdx.x;
    const int bi = blockIdx.x;            // 512 = 4b x 8h x 16 lc
    const int lc = bi & 15, h = (bi >> 4) & 7, b = bi >> 7;
    const size_t rbase = (size_t)(b * 8 + h) * 1024 + lc * 64;
    const _Float16* Sb = S + rbase * 1024;
    const float* ivb = invp + rbase;
    const int m0 = t * 4;

    float a0 = 0.f, a1 = 0.f, a2 = 0.f, a3 = 0.f;
    #pragma unroll 8
    for (int l = 0; l < 64; ++l) {
        const float iv = ivb[l];
        half4v e = *(const half4v*)&Sb[(size_t)l * 1024 + m0];
        a0 += (float)e[0] * iv;
        a1 += (float)e[1] * iv;
        a2 += (float)e[2] * iv;
        a3 += (float)e[3] * iv;
    }
    float* wb = wacc + b * 1024 + m0;
    atomicAdd(&wb[0], a0);
    atomicAdd(&wb[1], a1);
    atomicAdd(&wb[2], a2);
    atomicAdd(&wb[3], a3);
}

// ---------- w finalize: w = softmax_m( (wacc/8)/len ), invalid -> 0
__global__ __launch_bounds__(256) void w_final(
    const float* __restrict__ wacc, const float* __restrict__ doc,
    float* __restrict__ wout)
{
    const int b = blockIdx.x;
    const int t = threadIdx.x;
    __shared__ float red[4];

    const float ds = doc[b];
    const int len = (int)ds;

    float v[4];
    float mx = -INFINITY;
    #pragma unroll
    for (int i = 0; i < 4; ++i) {
        const int m = t + 256 * i;
        const float raw = wacc[b * L_ + m];
        v[i] = (m < len) ? (raw * 0.125f) / ds : -INFINITY;
        mx = fmaxf(mx, v[i]);
    }
    #pragma unroll
    for (int off = 1; off < 64; off <<= 1) mx = fmaxf(mx, __shfl_xor(mx, off));
    if ((t & 63) == 0) red[t >> 6] = mx;
    __syncthreads();
    mx = fmaxf(fmaxf(red[0], red[1]), fmaxf(red[2], red[3]));

    float e[4];
    float sm = 0.f;
    #pragma unroll
    for (int i = 0; i < 4; ++i) {
        e[i] = (v[i] != -INFINITY) ? __expf(v[i] - mx) : 0.f;
        sm += e[i];
    }
    #pragma unroll
    for (int off = 1; off < 64; off <<= 1) sm += __shfl_xor(sm, off);
    __syncthreads();
    if ((t & 63) == 0) red[t >> 6] = sm;
    __syncthreads();
    sm = red[0] + red[1] + red[2] + red[3];
    const float inv = (sm > 0.f) ? 1.0f / sm : 0.f;

    #pragma unroll
    for (int i = 0; i < 4; ++i)
        wout[b * L_ + t + 256 * i] = e[i] * inv;
}

extern "C" void kernel_launch(void* const* d_in, const int* in_sizes, int n_in,
                              void* d_out, int out_size, void* d_ws, size_t ws_size,
                              hipStream_t stream)
{
    const float* K     = (const float*)d_in[0];
    const float* Q     = (const float*)d_in[1];
    const float* V     = (const float*)d_in[2];
    const float* doc   = (const float*)d_in[3];
    const float* gamma = (const float*)d_in[4];
    const float* beta  = (const float*)d_in[5];

    float* out  = (float*)d_out;
    float* wout = out + (size_t)4 * L_ * D_;

    _Float16* S    = (_Float16*)d_ws;               // 64 MB (e-values)
    _Float16* K16  = S + (size_t)33554432;          // +4 MB
    _Float16* Q16  = K16 + 2097152;                 // +4 MB
    _Float16* Vt   = Q16 + 2097152;                 // +4 MB
    float*    spart = (float*)(Vt + 2097152);       // 2 MB (32768 x 16)
    float*    invp  = spart + 524288;               // 128 KB
    float*    wacc  = invp + 32768;                 // 16 KB

    hipMemsetAsync(wacc, 0, 4096 * sizeof(float), stream);
    prep        <<<dim3(768),  dim3(256), 0, stream>>>(K, Q, V, K16, Q16, Vt);
    qk_ln       <<<dim3(1024), dim3(256), 0, stream>>>(K16, Q16, gamma, beta, doc, S, spart);
    stats_reduce<<<dim3(128),  dim3(256), 0, stream>>>(spart, doc, invp);
    pv          <<<dim3(512),  dim3(256), 0, stream>>>(S, Vt, invp, out);
    wsum        <<<dim3(512),  dim3(256), 0, stream>>>(S, invp, wacc);
    w_final     <<<dim3(4),    dim3(256), 0, stream>>>(wacc, doc, wout);
}

// Round 3
// 207.745 us; speedup vs baseline: 1.0317x; 1.0317x over previous
//
#include <hip/hip_runtime.h>
#include <math.h>

// B=4, L=1024, D=512, H=8, d=64
#define L_ 1024
#define D_ 512

typedef _Float16 half8 __attribute__((ext_vector_type(8)));
typedef _Float16 half4v __attribute__((ext_vector_type(4)));
typedef _Float16 half2v __attribute__((ext_vector_type(2)));
typedef float floatx4 __attribute__((ext_vector_type(4)));

// S layout is TILED: S[bh][mtile(64)][l(1024)][mi(16)]  (halves)
//   addr = bh*1048576 + mtile*16384 + l*16 + mi
// This makes qk_ln's stores dense 512B wave-stores (no LDS staging), keeps
// pv's 16B fragment loads intact, and gives wsum contiguous 1KB wave reads.

// ---------- prep: K,Q -> fp16 straight; V -> fp16 transposed Vt[b][h][d][m]
__global__ __launch_bounds__(256) void prep(
    const float* __restrict__ K, const float* __restrict__ Q,
    const float* __restrict__ V,
    _Float16* __restrict__ K16, _Float16* __restrict__ Q16,
    _Float16* __restrict__ Vt)
{
    __shared__ _Float16 tile[64][72];
    const int t = threadIdx.x;
    const int bi = blockIdx.x;
    if (bi < 512) {
        for (int it = 0; it < 8; ++it) {
            size_t f = (size_t)bi * 2048 + it * 256 + t;
            const float4* src; _Float16* dst;
            if (f < 524288) { src = (const float4*)K; dst = K16; }
            else            { src = (const float4*)Q; dst = Q16; f -= 524288; }
            float4 v = src[f];
            half4v h = { (_Float16)v.x, (_Float16)v.y, (_Float16)v.z, (_Float16)v.w };
            *(half4v*)&dst[f * 4] = h;
        }
    } else {
        const int id = bi - 512;            // 512 blocks: 4b x 8h x 16 mtiles
        const int mt = id & 15, h = (id >> 4) & 7, b = id >> 7;
        const float4* Vf4 = (const float4*)V;
        for (int it = 0; it < 4; ++it) {
            const int ml = (t >> 4) + 16 * it;
            const int c4 = t & 15;
            float4 v = Vf4[(size_t)(b * 1024 + mt * 64 + ml) * 128 + h * 16 + c4];
            tile[c4 * 4 + 0][ml] = (_Float16)v.x;
            tile[c4 * 4 + 1][ml] = (_Float16)v.y;
            tile[c4 * 4 + 2][ml] = (_Float16)v.z;
            tile[c4 * 4 + 3][ml] = (_Float16)v.w;
        }
        __syncthreads();
        const int d = t >> 2, seg = t & 3;
        half8 o0 = *(half8*)&tile[d][seg * 16];
        half8 o1 = *(half8*)&tile[d][seg * 16 + 8];
        size_t obase = ((size_t)(b * 8 + h) * 64 + d) * 1024 + mt * 64 + seg * 16;
        *(half8*)&Vt[obase] = o0;
        *(half8*)&Vt[obase + 8] = o1;
    }
}

// ---------- qk_ln: e = exp(LN(K.Q^T) - M), LDS-free.
// MFMA operands are SWAPPED vs the classic layout: D = Q_frag x K_frag, so
// output col = l (K row) and row(quad*4+r) = m (Q row). Each lane then holds
// 4 consecutive m's for one l -> a half4 per (h,lane), stored as one dense
// 512B wave-store into the tiled S. No __syncthreads anywhere.
// M = max_h(2.8285*|gamma_h|+|beta_h|) bounds LN output, so exp never
// overflows without a per-row max pass.
__global__ __launch_bounds__(256) void qk_ln(
    const _Float16* __restrict__ K16, const _Float16* __restrict__ Q16,
    const float* __restrict__ gamma, const float* __restrict__ beta,
    const float* __restrict__ doc,
    _Float16* __restrict__ S, float* __restrict__ spart)
{
    const int t  = threadIdx.x;
    const int bi = blockIdx.x;              // 1024 = 4b x 64 lt x 4 q
    const int b  = bi & 3;
    const int lt = (bi >> 2) & 63;
    const int q  = bi >> 8;
    const int wv = t >> 6, lane = t & 63;
    const int col = lane & 15, quad = lane >> 4;
    const int len = (int)doc[b];
    const int lbase = lt * 16;

    float g[8], be[8], M = 0.f;
    #pragma unroll
    for (int h = 0; h < 8; ++h) {
        g[h] = gamma[h]; be[h] = beta[h];
        M = fmaxf(M, 2.8285f * fabsf(g[h]) + fabsf(be[h]));
    }

    const _Float16* Kb = K16 + (size_t)b * 524288;
    const _Float16* Qb = Q16 + (size_t)b * 524288;
    const size_t krow = (size_t)(lbase + col) * 512;
    const bool lok = (lbase + col) < len;

    float sum[8];
    #pragma unroll
    for (int h = 0; h < 8; ++h) sum[h] = 0.f;

    #pragma unroll
    for (int mt = 0; mt < 4; ++mt) {
        const int mstart = q * 256 + mt * 64 + wv * 16;
        const size_t qrow = (size_t)(mstart + col) * 512;
        floatx4 c[8];
        #pragma unroll
        for (int h = 0; h < 8; ++h) {
            // A = Q rows (m), B = K rows (l). K re-read per mt stays L1-hot.
            half8 qa0 = *(const half8*)&Qb[qrow + h * 64 + quad * 8];
            half8 qa1 = *(const half8*)&Qb[qrow + h * 64 + 32 + quad * 8];
            half8 kb0 = *(const half8*)&Kb[krow + h * 64 + quad * 8];
            half8 kb1 = *(const half8*)&Kb[krow + h * 64 + 32 + quad * 8];
            floatx4 z = {0.f, 0.f, 0.f, 0.f};
            z    = __builtin_amdgcn_mfma_f32_16x16x32_f16(qa0, kb0, z, 0, 0, 0);
            c[h] = __builtin_amdgcn_mfma_f32_16x16x32_f16(qa1, kb1, z, 0, 0, 0);
        }
        // lane holds: l = lbase+col, m = mstart + quad*4 + r
        half4v ev[8];
        #pragma unroll
        for (int r = 0; r < 4; ++r) {
            float mu = 0.f;
            #pragma unroll
            for (int h = 0; h < 8; ++h) mu += c[h][r];
            mu *= 0.125f;
            float var = 0.f;
            #pragma unroll
            for (int h = 0; h < 8; ++h) { float dd = c[h][r] - mu; var += dd * dd; }
            var *= 0.125f;
            const float rs = 1.0f / sqrtf(var + 1e-5f);
            const bool keep = lok && (mstart + quad * 4 + r) < len;
            #pragma unroll
            for (int h = 0; h < 8; ++h) {
                float e = 0.f;
                if (keep) e = __expf((c[h][r] - mu) * rs * g[h] + be[h] - M);
                sum[h] += e;
                ev[h][r] = (_Float16)e;
            }
        }
        const int mtile = q * 16 + mt * 4 + wv;
        #pragma unroll
        for (int h = 0; h < 8; ++h) {
            // 64 lanes x 8B = one dense 512B region (16 l x 32B)
            *(half4v*)&S[((size_t)((b * 8 + h) * 64 + mtile)) * 16384
                         + (size_t)(lbase + col) * 16 + quad * 4] = ev[h];
        }
    }

    // row partial sums: lane sums its 4 m's per mt (done above); combine the
    // 4 quads (m-chunks) -> per-l sum over this wave's 64 m's.
    #pragma unroll
    for (int h = 0; h < 8; ++h) {
        float s = sum[h];
        s += __shfl_xor(s, 16); s += __shfl_xor(s, 32);
        sum[h] = s;
    }
    if (quad == 0) {
        #pragma unroll
        for (int h = 0; h < 8; ++h)
            spart[((size_t)((b * 8 + h) * 1024 + lbase + col)) * 16 + q * 4 + wv] =
                sum[h];
    }
}

// ---------- stats_reduce: inv[row] = 1/sum(e) (0 for padded rows)
__global__ __launch_bounds__(256) void stats_reduce(
    const float* __restrict__ spart, const float* __restrict__ doc,
    float* __restrict__ inv)
{
    const int i = blockIdx.x * 256 + threadIdx.x;   // 32768 rows
    const int l = i & 1023;
    const int b = i >> 13;
    const int len = (int)doc[b];
    float s = 0.f;
    #pragma unroll
    for (int j = 0; j < 16; ++j) s += spart[(size_t)i * 16 + j];
    inv[i] = (l < len && s > 0.f) ? 1.0f / s : 0.f;
}

// ---------- pv: pure streaming PV MFMA on raw fp16 e (tiled S layout);
// normalization applied to the fp32 accumulator in the epilogue. No LDS,
// no shuffles, no atomics. 8-deep register ring prefetch; Vt L2-resident.
__global__ __launch_bounds__(256) void pv(
    const _Float16* __restrict__ S, const _Float16* __restrict__ Vt,
    const float* __restrict__ invp,
    float* __restrict__ out)
{
    const int t = threadIdx.x, wv = t >> 6, lane = t & 63;
    const int col = lane & 15, quad = lane >> 4;
    const int bi = blockIdx.x;            // 512 = 4b x 8h x 16 lb
    const int lb = bi & 15, h = (bi >> 4) & 7, b = bi >> 7;
    const int l0 = lb * 64 + wv * 16;

    // tiled S: m = kc*32 + quad*8 + j  ->  tile = kc*2 + (quad>>1),
    // within-tile offset (quad&1)*8 (identical m set as the flat layout)
    const int q2 = quad >> 1;
    const size_t abase = (size_t)(b * 8 + h) * 1048576
                       + (size_t)(l0 + col) * 16 + (quad & 1) * 8;
    const _Float16* Vb = Vt + (size_t)(b * 8 + h) * 65536;

    floatx4 acc[4] = {{0,0,0,0},{0,0,0,0},{0,0,0,0},{0,0,0,0}};

    half8 ebuf[8];
    #pragma unroll
    for (int i = 0; i < 8; ++i)
        ebuf[i] = *(const half8*)&S[abase + (size_t)(i * 2 + q2) * 16384];

    #pragma unroll
    for (int kc = 0; kc < 32; ++kc) {
        half8 a = ebuf[kc & 7];
        if (kc + 8 < 32)
            ebuf[kc & 7] = *(const half8*)&S[abase + (size_t)((kc + 8) * 2 + q2) * 16384];
        #pragma unroll
        for (int dt = 0; dt < 4; ++dt) {
            half8 bf = *(const half8*)&Vb[(size_t)(dt * 16 + col) * 1024
                                          + kc * 32 + quad * 8];
            acc[dt] = __builtin_amdgcn_mfma_f32_16x16x32_f16(a, bf, acc[dt], 0, 0, 0);
        }
    }

    #pragma unroll
    for (int r = 0; r < 4; ++r) {
        const int l = l0 + quad * 4 + r;
        const float ivr = invp[(size_t)(b * 8 + h) * 1024 + l];
        float* orow = out + (size_t)(b * 1024 + l) * 512 + h * 64;
        #pragma unroll
        for (int dt = 0; dt < 4; ++dt)
            orow[dt * 16 + col] = acc[dt][r] * ivr;
    }
}

// ---------- wsum: w column sums over the tiled S layout.
// Each wave owns one 16-m tile and streams its [l][16] slab contiguously
// (64 lanes x 16B = 1KB per iteration). Per-thread fp32 register
// accumulation of 8 m's; cross-lane reduce over the 32 l-offset groups at
// the end; one atomicAdd per (m) per block.
__global__ __launch_bounds__(256) void wsum(
    const _Float16* __restrict__ S, const float* __restrict__ invp,
    float* __restrict__ wacc)
{
    const int t = threadIdx.x, lane = t & 63;
    const int bi = blockIdx.x;            // 512 = 4b x 8h x 16 tg
    const int tg = bi & 15, h = (bi >> 4) & 7, b = bi >> 7;
    const int tile = tg * 4 + (t >> 6);   // one tile per wave
    const int loff = lane >> 1, hi = lane & 1;
    const _Float16* Sb = S + ((size_t)((b * 8 + h) * 64 + tile)) * 16384 + hi * 8;
    const float* ivb = invp + (size_t)(b * 8 + h) * 1024;

    float acc[8];
    #pragma unroll
    for (int j = 0; j < 8; ++j) acc[j] = 0.f;

    for (int l0 = 0; l0 < 1024; l0 += 128) {
        #pragma unroll
        for (int u = 0; u < 4; ++u) {
            const int l = l0 + u * 32 + loff;
            const float iv = ivb[l];
            half8 e = *(const half8*)&Sb[(size_t)l * 16];
            #pragma unroll
            for (int j = 0; j < 8; ++j) acc[j] += (float)e[j] * iv;
        }
    }
    #pragma unroll
    for (int j = 0; j < 8; ++j) {
        float s = acc[j];
        s += __shfl_xor(s, 2);  s += __shfl_xor(s, 4);
        s += __shfl_xor(s, 8);  s += __shfl_xor(s, 16);
        s += __shfl_xor(s, 32);
        acc[j] = s;
    }
    if (lane < 2) {
        float* wb = wacc + b * 1024 + tile * 16 + hi * 8;
        #pragma unroll
        for (int j = 0; j < 8; ++j) atomicAdd(&wb[j], acc[j]);
    }
}

// ---------- w finalize: w = softmax_m( (wacc/8)/len ), invalid -> 0
__global__ __launch_bounds__(256) void w_final(
    const float* __restrict__ wacc, const float* __restrict__ doc,
    float* __restrict__ wout)
{
    const int b = blockIdx.x;
    const int t = threadIdx.x;
    __shared__ float red[4];

    const float ds = doc[b];
    const int len = (int)ds;

    float v[4];
    float mx = -INFINITY;
    #pragma unroll
    for (int i = 0; i < 4; ++i) {
        const int m = t + 256 * i;
        const float raw = wacc[b * L_ + m];
        v[i] = (m < len) ? (raw * 0.125f) / ds : -INFINITY;
        mx = fmaxf(mx, v[i]);
    }
    #pragma unroll
    for (int off = 1; off < 64; off <<= 1) mx = fmaxf(mx, __shfl_xor(mx, off));
    if ((t & 63) == 0) red[t >> 6] = mx;
    __syncthreads();
    mx = fmaxf(fmaxf(red[0], red[1]), fmaxf(red[2], red[3]));

    float e[4];
    float sm = 0.f;
    #pragma unroll
    for (int i = 0; i < 4; ++i) {
        e[i] = (v[i] != -INFINITY) ? __expf(v[i] - mx) : 0.f;
        sm += e[i];
    }
    #pragma unroll
    for (int off = 1; off < 64; off <<= 1) sm += __shfl_xor(sm, off);
    __syncthreads();
    if ((t & 63) == 0) red[t >> 6] = sm;
    __syncthreads();
    sm = red[0] + red[1] + red[2] + red[3];
    const float inv = (sm > 0.f) ? 1.0f / sm : 0.f;

    #pragma unroll
    for (int i = 0; i < 4; ++i)
        wout[b * L_ + t + 256 * i] = e[i] * inv;
}

extern "C" void kernel_launch(void* const* d_in, const int* in_sizes, int n_in,
                              void* d_out, int out_size, void* d_ws, size_t ws_size,
                              hipStream_t stream)
{
    const float* K     = (const float*)d_in[0];
    const float* Q     = (const float*)d_in[1];
    const float* V     = (const float*)d_in[2];
    const float* doc   = (const float*)d_in[3];
    const float* gamma = (const float*)d_in[4];
    const float* beta  = (const float*)d_in[5];

    float* out  = (float*)d_out;
    float* wout = out + (size_t)4 * L_ * D_;

    _Float16* S    = (_Float16*)d_ws;               // 64 MB (e-values, tiled)
    _Float16* K16  = S + (size_t)33554432;          // +4 MB
    _Float16* Q16  = K16 + 2097152;                 // +4 MB
    _Float16* Vt   = Q16 + 2097152;                 // +4 MB
    float*    spart = (float*)(Vt + 2097152);       // 2 MB (32768 x 16)
    float*    invp  = spart + 524288;               // 128 KB
    float*    wacc  = invp + 32768;                 // 16 KB

    hipMemsetAsync(wacc, 0, 4096 * sizeof(float), stream);
    prep        <<<dim3(1024), dim3(256), 0, stream>>>(K, Q, V, K16, Q16, Vt);
    qk_ln       <<<dim3(1024), dim3(256), 0, stream>>>(K16, Q16, gamma, beta, doc, S, spart);
    stats_reduce<<<dim3(128),  dim3(256), 0, stream>>>(spart, doc, invp);
    pv          <<<dim3(512),  dim3(256), 0, stream>>>(S, Vt, invp, out);
    wsum        <<<dim3(512),  dim3(256), 0, stream>>>(S, invp, wacc);
    w_final     <<<dim3(4),    dim3(256), 0, stream>>>(wacc, doc, wout);
}